// Round 12
// baseline (3517.086 us; speedup 1.0000x reference)
//
#include <hip/hip_runtime.h>

#define NB 256      // batch
#define TT 1000     // total timesteps
#define HD 128      // hidden
#define NG 512      // 4*H, PyTorch gate order i,f,g,o
#define SS 8        // K2: timesteps per LDS slab

#define WGA __attribute__((amdgpu_flat_work_group_size(512,512), amdgpu_waves_per_eu(2,2)))

typedef __attribute__((ext_vector_type(8))) short s8v;   // 8 bf16 = 4 VGPR (MFMA A/B)
typedef __attribute__((ext_vector_type(4))) float f4v;   // MFMA C/D

__device__ __forceinline__ unsigned short bf16rne(float v) {
    unsigned u = __float_as_uint(v);
    unsigned r = u + 0x7FFF + ((u >> 16) & 1);
    return (unsigned short)(r >> 16);
}
__device__ __forceinline__ float bf16tof(unsigned short h) {
    return __uint_as_float(((unsigned)h) << 16);
}
__device__ __forceinline__ float sigf(float x) { return 1.f / (1.f + __expf(-x)); }
__device__ __forceinline__ float tanhfast(float x) {
    float e = __expf(-2.f * x);
    return 2.f / (1.f + e) - 1.f;
}

// Load W rows [64*wv, 64*wv+64) as hi/lo bf16 A-fragments.
// A-fragment map (16x16x32): m = lane&15, k = (lane>>4)*4 + (e&3) + 16*(e>>2).
#define LOAD_A(W)                                                              \
    {                                                                          \
        _Pragma("unroll")                                                      \
        for (int t = 0; t < 4; ++t) {                                          \
            const int m = 64*wv + 16*t + lm;                                   \
            const float* wrow = (W) + (size_t)m * HD;                          \
            _Pragma("unroll")                                                  \
            for (int kc = 0; kc < 4; ++kc) {                                   \
                const int k0 = 32*kc + 4*lq;                                   \
                float4 va = *(const float4*)(wrow + k0);                       \
                float4 vb = *(const float4*)(wrow + k0 + 16);                  \
                float vs[8] = {va.x,va.y,va.z,va.w,vb.x,vb.y,vb.z,vb.w};       \
                s8v ah, al;                                                    \
                _Pragma("unroll")                                              \
                for (int e = 0; e < 8; ++e) {                                  \
                    unsigned short hb = bf16rne(vs[e]);                        \
                    float lo = vs[e] - bf16tof(hb);                            \
                    ah[e] = (short)hb; al[e] = (short)bf16rne(lo);             \
                }                                                              \
                Ah[t][kc] = ah; Al[t][kc] = al;                                \
            }                                                                  \
        }                                                                      \
    }

// Build B fragments (h replicated across all 16 N-cols) from packed bf16 LDS.
// B map: n = lane&15 (don't care, replicated), k = (lane>>4)*4+(e&3)+16*(e>>2).
#define BUILD_B(hhi, hlo)                                                      \
    {                                                                          \
        _Pragma("unroll")                                                      \
        for (int kc = 0; kc < 4; ++kc) {                                       \
            const int k0 = 32*kc + 4*lq;                                       \
            union { uint4 u; s8v s; } cv;                                      \
            uint2 pa = *(const uint2*)&(hhi)[k0];                              \
            uint2 pb = *(const uint2*)&(hhi)[k0+16];                           \
            cv.u.x = pa.x; cv.u.y = pa.y; cv.u.z = pb.x; cv.u.w = pb.y;        \
            Bh[kc] = cv.s;                                                     \
            uint2 qa = *(const uint2*)&(hlo)[k0];                              \
            uint2 qb = *(const uint2*)&(hlo)[k0+16];                           \
            cv.u.x = qa.x; cv.u.y = qa.y; cv.u.z = qb.x; cv.u.w = qb.y;        \
            Bl[kc] = cv.s;                                                     \
        }                                                                      \
    }

// 3-pass hi/lo MFMA: D = Ah*Bh + Al*Bh + Ah*Bl, fp32 accumulate.
// Lanes lm==0 (lq=0..3) write D rows 16t+4*lq+r to gbuf (raw, pre-activation).
#define MFMA_GATES()                                                           \
    {                                                                          \
        _Pragma("unroll")                                                      \
        for (int t = 0; t < 4; ++t) {                                          \
            f4v aP = {0.f,0.f,0.f,0.f}, aQ = {0.f,0.f,0.f,0.f},                \
                aR = {0.f,0.f,0.f,0.f};                                        \
            _Pragma("unroll")                                                  \
            for (int kc = 0; kc < 4; ++kc) {                                   \
                aP = __builtin_amdgcn_mfma_f32_16x16x32_bf16(Ah[t][kc], Bh[kc], aP, 0,0,0); \
                aQ = __builtin_amdgcn_mfma_f32_16x16x32_bf16(Al[t][kc], Bh[kc], aQ, 0,0,0); \
                aR = __builtin_amdgcn_mfma_f32_16x16x32_bf16(Ah[t][kc], Bl[kc], aR, 0,0,0); \
            }                                                                  \
            if (lm == 0) {                                                     \
                float4 o;                                                      \
                o.x = aP[0]+aQ[0]+aR[0]; o.y = aP[1]+aQ[1]+aR[1];              \
                o.z = aP[2]+aQ[2]+aR[2]; o.w = aP[3]+aQ[3]+aR[3];              \
                *(float4*)&gbuf[64*wv + 16*t + 4*lq] = o;                      \
            }                                                                  \
        }                                                                      \
    }

// ---------------- K1: layer-0 recurrence, MFMA hi/lo ----------------
__global__ WGA
void lstm_layer0(const float* __restrict__ x,
                 const float* __restrict__ Wih, const float* __restrict__ Whh,
                 const float* __restrict__ bih, const float* __restrict__ bhh,
                 float* __restrict__ h1c,
                 float* __restrict__ hstate, float* __restrict__ cstate,
                 int t0, int len)
{
    __shared__ unsigned short hhi[HD], hlo[HD];   // h as bf16 hi/lo
    __shared__ float gbuf[NG];                    // raw gates (pre-activation)
    __shared__ float x_lds[3 * TT];               // 12 KB
    const int j = threadIdx.x;
    const int b = blockIdx.x;
    const int wv = j >> 6, lane = j & 63, lq = lane >> 4, lm = lane & 15;

    s8v Ah[4][4], Al[4][4];      // W_hh fragments -> AGPR-resident (MFMA reads them)
    LOAD_A(Whh);

    // update-thread constants (waves 0-1 only meaningful)
    float wx[12], bs[4];
    if (j < HD) {
        #pragma unroll
        for (int g = 0; g < 4; ++g) {
            const int r = g*HD + j;
            wx[3*g+0] = Wih[r*3+0]; wx[3*g+1] = Wih[r*3+1]; wx[3*g+2] = Wih[r*3+2];
            bs[g] = bih[r] + bhh[r];
        }
    }

    for (int idx = j; idx < 3*len; idx += 512)
        x_lds[idx] = x[((size_t)b*TT + t0)*3 + idx];

    float c = 0.f, hcur = 0.f;
    if (j < HD) {
        if (t0 != 0) { hcur = hstate[b*HD+j]; c = cstate[b*HD+j]; }
        unsigned short hb = bf16rne(hcur);
        hhi[j] = hb; hlo[j] = bf16rne(hcur - bf16tof(hb));
    }
    __syncthreads();

    for (int tc = 0; tc < len; ++tc) {
        s8v Bh[4], Bl[4];
        BUILD_B(hhi, hlo);
        MFMA_GATES();
        __syncthreads();                 // barrier A: raw gates visible
        if (j < HD) {
            const float x0 = x_lds[3*tc+0], x1 = x_lds[3*tc+1], x2 = x_lds[3*tc+2];
            float gi = gbuf[j]      + bs[0] + wx[0]*x0 + wx[1]*x1 + wx[2]*x2;
            float gf = gbuf[HD+j]   + bs[1] + wx[3]*x0 + wx[4]*x1 + wx[5]*x2;
            float gg = gbuf[2*HD+j] + bs[2] + wx[6]*x0 + wx[7]*x1 + wx[8]*x2;
            float go = gbuf[3*HD+j] + bs[3] + wx[9]*x0 + wx[10]*x1 + wx[11]*x2;
            float iv = sigf(gi), fv = sigf(gf), gv = tanhfast(gg), ov = sigf(go);
            c = fmaf(fv, c, iv*gv);
            hcur = ov * tanhfast(c);
            h1c[((size_t)b*len + tc)*HD + j] = hcur;
            unsigned short hb = bf16rne(hcur);
            hhi[j] = hb; hlo[j] = bf16rne(hcur - bf16tof(hb));
        }
        __syncthreads();                 // barrier B: new h visible
    }
    if (j < HD) { hstate[b*HD+j] = hcur; cstate[b*HD+j] = c; }
}

// ---------------- K2: xg1 = h1 @ W_ih_l1^T + biases (fp32, r10 version) ----------------
#define DOT128(h4, wvv, A0, A1, A2, A3)                                        \
    {                                                                          \
        float4 c0=(h4)[0], c1=(h4)[1], c2=(h4)[2], c3=(h4)[3];                 \
        _Pragma("unroll")                                                      \
        for (int g = 0; g < 8; ++g) {                                          \
            float4 n0,n1,n2,n3;                                                \
            if (g < 7) { n0=(h4)[4*g+4]; n1=(h4)[4*g+5];                       \
                         n2=(h4)[4*g+6]; n3=(h4)[4*g+7]; }                     \
            A0 = fmaf(c0.x, wvv[4*g+0].x, A0); A1 = fmaf(c0.y, wvv[4*g+0].y, A1);\
            A2 = fmaf(c0.z, wvv[4*g+0].z, A2); A3 = fmaf(c0.w, wvv[4*g+0].w, A3);\
            A0 = fmaf(c1.x, wvv[4*g+1].x, A0); A1 = fmaf(c1.y, wvv[4*g+1].y, A1);\
            A2 = fmaf(c1.z, wvv[4*g+1].z, A2); A3 = fmaf(c1.w, wvv[4*g+1].w, A3);\
            A0 = fmaf(c2.x, wvv[4*g+2].x, A0); A1 = fmaf(c2.y, wvv[4*g+2].y, A1);\
            A2 = fmaf(c2.z, wvv[4*g+2].z, A2); A3 = fmaf(c2.w, wvv[4*g+2].w, A3);\
            A0 = fmaf(c3.x, wvv[4*g+3].x, A0); A1 = fmaf(c3.y, wvv[4*g+3].y, A1);\
            A2 = fmaf(c3.z, wvv[4*g+3].z, A2); A3 = fmaf(c3.w, wvv[4*g+3].w, A3);\
            __builtin_amdgcn_sched_barrier(0);                                 \
            if (g < 7) { c0=n0; c1=n1; c2=n2; c3=n3; }                         \
        }                                                                      \
    }

__global__ WGA
void xgate_gemm(const float* __restrict__ h1c,
                const float* __restrict__ Wih1,
                const float* __restrict__ bih1, const float* __restrict__ bhh1,
                float* __restrict__ xg1c, int len)
{
    __shared__ __align__(16) float hrows[SS][HD];   // 4 KB
    const int j = threadIdx.x;
    const int b = blockIdx.x;
    float4 wvv[HD/4];
    {
        const float4* wr = (const float4*)(Wih1 + (size_t)j * HD);
        #pragma unroll
        for (int q = 0; q < HD/4; ++q) wvv[q] = wr[q];
    }
    const float bias = bih1[j] + bhh1[j];

    for (int ts = 0; ts < len; ts += SS) {
        const int ns = (len - ts < SS) ? (len - ts) : SS;
        __syncthreads();
        for (int idx = j; idx < ns * HD; idx += 512)
            hrows[idx >> 7][idx & 127] = h1c[((size_t)b*len + ts)*HD + idx];
        __syncthreads();
        for (int s = 0; s < ns; ++s) {
            float a0=0.f,a1=0.f,a2=0.f,a3=0.f;
            const float4* h4 = (const float4*)hrows[s];
            DOT128(h4, wvv, a0, a1, a2, a3);
            xg1c[((size_t)b*len + ts + s)*NG + j] = bias + ((a0+a1)+(a2+a3));
        }
    }
}

// ---------------- K3: layer-1 recurrence, MFMA hi/lo ----------------
__global__ WGA
void lstm_layer1(const float* __restrict__ xg1c,
                 const float* __restrict__ Whh1,
                 float* __restrict__ h2c,
                 float* __restrict__ hstate, float* __restrict__ cstate,
                 int t0, int len)
{
    __shared__ unsigned short hhi[HD], hlo[HD];
    __shared__ float gbuf[NG];
    const int j = threadIdx.x;
    const int b = blockIdx.x;
    const int wv = j >> 6, lane = j & 63, lq = lane >> 4, lm = lane & 15;

    s8v Ah[4][4], Al[4][4];      // W_hh_l1 fragments
    LOAD_A(Whh1);

    float c = 0.f, hcur = 0.f;
    if (j < HD) {
        if (t0 != 0) { hcur = hstate[b*HD+j]; c = cstate[b*HD+j]; }
        unsigned short hb = bf16rne(hcur);
        hhi[j] = hb; hlo[j] = bf16rne(hcur - bf16tof(hb));
    }
    __syncthreads();

    float xg0=0.f, xg1=0.f, xg2=0.f, xg3=0.f;
    if (j < HD) {
        const float* xr = xg1c + ((size_t)b*len + 0)*NG;
        xg0 = xr[j]; xg1 = xr[HD+j]; xg2 = xr[2*HD+j]; xg3 = xr[3*HD+j];
    }
    for (int tc = 0; tc < len; ++tc) {
        float n0=0.f,n1=0.f,n2=0.f,n3=0.f;
        if (j < HD && tc+1 < len) {    // prefetch next xg row
            const float* xr = xg1c + ((size_t)b*len + tc+1)*NG;
            n0 = xr[j]; n1 = xr[HD+j]; n2 = xr[2*HD+j]; n3 = xr[3*HD+j];
        }
        s8v Bh[4], Bl[4];
        BUILD_B(hhi, hlo);
        MFMA_GATES();
        __syncthreads();                 // barrier A
        if (j < HD) {
            float gi = gbuf[j]      + xg0;   // K2 folded biases in
            float gf = gbuf[HD+j]   + xg1;
            float gg = gbuf[2*HD+j] + xg2;
            float go = gbuf[3*HD+j] + xg3;
            float iv = sigf(gi), fv = sigf(gf), gv = tanhfast(gg), ov = sigf(go);
            c = fmaf(fv, c, iv*gv);
            hcur = ov * tanhfast(c);
            h2c[((size_t)b*len + tc)*HD + j] = hcur;
            unsigned short hb = bf16rne(hcur);
            hhi[j] = hb; hlo[j] = bf16rne(hcur - bf16tof(hb));
        }
        __syncthreads();                 // barrier B
        xg0=n0; xg1=n1; xg2=n2; xg3=n3;
    }
    if (j < HD) { hstate[b*HD+j] = hcur; cstate[b*HD+j] = c; }
}

// ---------------- K4: y = h2 @ fcw^T + fcb — wave-per-row, fp32 ----------------
__global__ __launch_bounds__(512, 1)
void fc_head(const float* __restrict__ h2c,
             const float* __restrict__ fcw, const float* __restrict__ fcb,
             float* __restrict__ y, int t0, int len)
{
    const int b = blockIdx.x;
    const int wid = threadIdx.x >> 6;
    const int lane = threadIdx.x & 63;
    const float f0a = fcw[0*HD+lane], f0b = fcw[0*HD+64+lane];
    const float f1a = fcw[1*HD+lane], f1b = fcw[1*HD+64+lane];
    const float f2a = fcw[2*HD+lane], f2b = fcw[2*HD+64+lane];
    const float fb = (lane < 3) ? fcb[lane] : 0.f;
    for (int tc = wid; tc < len; tc += 8) {
        const float* hp = h2c + ((size_t)b*len + tc)*HD;
        float ha = hp[lane], hb = hp[64+lane];
        float y0 = ha*f0a + hb*f0b;
        float y1 = ha*f1a + hb*f1b;
        float y2 = ha*f2a + hb*f2b;
        #pragma unroll
        for (int m = 1; m < 64; m <<= 1) {
            y0 += __shfl_xor(y0, m);
            y1 += __shfl_xor(y1, m);
            y2 += __shfl_xor(y2, m);
        }
        if (lane < 3) {
            float yv = (lane==0) ? y0 : (lane==1) ? y1 : y2;
            y[((size_t)b*TT + (t0+tc))*3 + lane] = yv + fb;
        }
    }
}

extern "C" void kernel_launch(void* const* d_in, const int* in_sizes, int n_in,
                              void* d_out, int out_size, void* d_ws, size_t ws_size,
                              hipStream_t stream)
{
    const float* x    = (const float*)d_in[0];
    const float* Wih0 = (const float*)d_in[1];
    const float* Whh0 = (const float*)d_in[2];
    const float* bih0 = (const float*)d_in[3];
    const float* bhh0 = (const float*)d_in[4];
    const float* Wih1 = (const float*)d_in[5];
    const float* Whh1 = (const float*)d_in[6];
    const float* bih1 = (const float*)d_in[7];
    const float* bhh1 = (const float*)d_in[8];
    const float* fcw  = (const float*)d_in[9];
    const float* fcb  = (const float*)d_in[10];
    float* y = (float*)d_out;

    const size_t stateBytes = 4ull * NB * HD * sizeof(float);
    const size_t perT = (size_t)NB*HD*sizeof(float) + (size_t)NB*NG*sizeof(float);
    long tcl = (ws_size > stateBytes) ? (long)((ws_size - stateBytes) / perT) : 1;
    if (tcl > TT) tcl = TT;
    if (tcl < 1)  tcl = 1;
    const int Tc = (int)tcl;

    float* h1c  = (float*)d_ws;
    float* xg1c = h1c  + (size_t)NB * Tc * HD;
    float* hs1  = xg1c + (size_t)NB * Tc * NG;
    float* cs1  = hs1 + NB*HD;
    float* hs2  = cs1 + NB*HD;
    float* cs2  = hs2 + NB*HD;
    float* h2c  = h1c;

    for (int t0 = 0; t0 < TT; t0 += Tc) {
        const int len = (TT - t0 < Tc) ? (TT - t0) : Tc;
        lstm_layer0<<<dim3(NB), dim3(512), 0, stream>>>(
            x, Wih0, Whh0, bih0, bhh0, h1c, hs1, cs1, t0, len);
        xgate_gemm<<<dim3(NB), dim3(512), 0, stream>>>(
            h1c, Wih1, bih1, bhh1, xg1c, len);
        lstm_layer1<<<dim3(NB), dim3(512), 0, stream>>>(
            xg1c, Whh1, h2c, hs2, cs2, t0, len);
        fc_head<<<dim3(NB), dim3(512), 0, stream>>>(
            h2c, fcw, fcb, y, t0, len);
    }
}